// Round 14
// baseline (18.907 us; speedup 1.0000x reference)
//
#include <hip/hip_runtime.h>

#define NATOMS 8192
#define NFREE  4096

constexpr int TPB = 256;            // threads per block (4 waves)
constexpr int IPT = 4;              // i-atoms per thread
constexpr int TI  = TPB * IPT;      // 1024 i-atoms per block
constexpr int JT  = 16;             // j-atoms, block-uniform, SGPR-resident
constexpr int GI  = NATOMS / TI;    // 8 i-slabs
constexpr int GJ  = NATOMS / JT;    // 512 j-tiles
constexpr int TPS = TI / JT;        // 64 j-tiles spanning one i-slab
// Triangle grid: slab x dispatches j-tiles y in [TPS*x, GJ) -> 512-64x blocks.
__device__ __constant__ const int S_START[GI + 1] = {
    0, 512, 960, 1344, 1664, 1920, 2112, 2240, 2304};
constexpr int NVBLK = 2304;         // 9 blocks/CU -> waves capped at 32/CU

__device__ __forceinline__ float wave_reduce(float v) {
#pragma unroll
    for (int off = 32; off > 0; off >>= 1)
        v += __shfl_down(v, off, 64);
    return v;
}

// Triangle all-pairs sum of 1/r over i<j, coords direct from q/x0
// (free_idx = arange(NFREE): atoms [0,NFREE) from q, rest from x0; slab/tile
// boundaries never straddle NFREE). r2 = si + sj - 2 xi.xj, (-2xi) prescaled.
// j-tile values are block-uniform scalars: the compiler scalarizes the loads
// (s_load) and the inner loop reads them straight from SGPRs -- the loop has
// ZERO memory operations, zero LDS, zero j-VGPR cost.
__global__ __launch_bounds__(TPB) void pair_kernel(const float* __restrict__ q,
                                                   const float* __restrict__ x0,
                                                   float* __restrict__ vpart) {
    const int bid = blockIdx.x;

    int x = 0;
#pragma unroll
    for (int e = 1; e < GI; ++e) x += (bid >= S_START[e]);
    const int y  = bid - S_START[x] + TPS * x;
    const int i0 = x * TI;
    const int j0 = y * JT;
    const int t  = threadIdx.x;

    // i-side: prescaled (-2x) and |x|^2 per thread.
    const float* isrc = (i0 < NFREE) ? q : x0;
    float axi[IPT], ayi[IPT], azi[IPT], si[IPT], acc[IPT];
    int m[IPT];
    const int rel0 = j0 - i0;
#pragma unroll
    for (int k = 0; k < IPT; ++k) {
        const int ia = i0 + t + k * TPB;
        float xx = isrc[3 * ia + 0], yy = isrc[3 * ia + 1], zz = isrc[3 * ia + 2];
        axi[k] = -2.f * xx;
        ayi[k] = -2.f * yy;
        azi[k] = -2.f * zz;
        si[k]  = fmaf(xx, xx, fmaf(yy, yy, zz * zz));
        acc[k] = 0.f;
        m[k] = t + k * TPB - rel0;   // keep iff m[k] < j_local (diag band only)
    }

    // j-side: block-uniform loads -> SGPRs (compiler-scalarized), hoisted.
    const float* jp = ((j0 < NFREE) ? q : x0) + 3 * j0;
    float jx[JT], jy[JT], jz[JT], jw[JT];
#pragma unroll
    for (int jj = 0; jj < JT; ++jj) {
        jx[jj] = jp[3 * jj + 0];
        jy[jj] = jp[3 * jj + 1];
        jz[jj] = jp[3 * jj + 2];
        jw[jj] = fmaf(jx[jj], jx[jj], fmaf(jy[jj], jy[jj], jz[jj] * jz[jj]));
    }

    if (rel0 < TI) {
        // Diagonal-band tile: keep only i<j (select also drops the i==j inf/NaN).
#pragma unroll
        for (int j = 0; j < JT; ++j) {
#pragma unroll
            for (int k = 0; k < IPT; ++k) {
                float d = fmaf(axi[k], jx[j], si[k]);
                d = fmaf(ayi[k], jy[j], d);
                d = fmaf(azi[k], jz[j], d);
                float rinv = __builtin_amdgcn_rsqf(d + jw[j]);
                acc[k] += (m[k] < j) ? rinv : 0.f;
            }
        }
    } else {
#pragma unroll
        for (int j = 0; j < JT; ++j) {
#pragma unroll
            for (int k = 0; k < IPT; ++k) {
                float d = fmaf(axi[k], jx[j], si[k]);
                d = fmaf(ayi[k], jy[j], d);
                d = fmaf(azi[k], jz[j], d);
                acc[k] += __builtin_amdgcn_rsqf(d + jw[j]);
            }
        }
    }

    float v = (acc[0] + acc[1]) + (acc[2] + acc[3]);
    v = wave_reduce(v);
    __shared__ float s[TPB / 64];
    int lane = t & 63, wid = t >> 6;
    if (lane == 0) s[wid] = v;
    __syncthreads();
    if (t == 0)
        vpart[bid] = (s[0] + s[1]) + (s[2] + s[3]);
}

// out = 0.5*sum(qd^2) - 2*sum(vpart); single block, deterministic order.
__global__ void finalize(const float* __restrict__ vpart,
                         const float4* __restrict__ qd4,   // qd as 3072 float4
                         float* __restrict__ out) {
    float v = 0.f;
    for (int i = threadIdx.x; i < NVBLK; i += 256) v += vpart[i];
    float tq = 0.f;
    for (int i = threadIdx.x; i < (NFREE * 3) / 4; i += 256) {
        float4 u = qd4[i];
        tq += fmaf(u.x, u.x, fmaf(u.y, u.y, fmaf(u.z, u.z, u.w * u.w)));
    }
    v = wave_reduce(v);
    tq = wave_reduce(tq);
    __shared__ float sv[4], st[4];
    int lane = threadIdx.x & 63, wid = threadIdx.x >> 6;
    if (lane == 0) { sv[wid] = v; st[wid] = tq; }
    __syncthreads();
    if (threadIdx.x == 0) {
        float V = (sv[0] + sv[1]) + (sv[2] + sv[3]);
        float T = (st[0] + st[1]) + (st[2] + st[3]);
        out[0] = 0.5f * T - 2.0f * V;   // V2 = 2 * sum_{i<j} 1/r
    }
}

extern "C" void kernel_launch(void* const* d_in, const int* in_sizes, int n_in,
                              void* d_out, int out_size, void* d_ws, size_t ws_size,
                              hipStream_t stream) {
    const float* q  = (const float*)d_in[0];
    const float* qd = (const float*)d_in[1];
    const float* x0 = (const float*)d_in[2];
    float* out = (float*)d_out;

    float* vpart = (float*)d_ws;

    pair_kernel<<<NVBLK, TPB, 0, stream>>>(q, x0, vpart);
    finalize<<<1, 256, 0, stream>>>(vpart, (const float4*)qd, out);
}

// Round 15
// 16.967 us; speedup vs baseline: 1.1143x; 1.1143x over previous
//
#include <hip/hip_runtime.h>

#define NATOMS 8192
#define NFREE  4096

constexpr int TPB = 256;            // threads per block (4 waves)
constexpr int IPT = 4;              // i-atoms per thread, CONSECUTIVE (float4 loads)
constexpr int TI  = TPB * IPT;      // 1024 i-atoms per block
constexpr int JT  = 32;             // j-atoms staged in LDS per block
constexpr int GI  = NATOMS / TI;    // 8 i-slabs
constexpr int GJ  = NATOMS / JT;    // 256 j-tiles
constexpr int TPS = TI / JT;        // 32 j-tiles spanning one i-slab
// Triangle grid: slab x dispatches j-tiles y in [TPS*x, GJ).
__device__ __constant__ const int S_START[GI + 1] = {0, 256, 480, 672, 832, 960, 1056, 1120, 1152};
constexpr int NVBLK = 1152;         // 4.5 blocks/CU -> all resident

typedef __attribute__((ext_vector_type(2))) float f32x2;

// d = a * broadcast(b.lo) + c   (VOP3P op_sel: both result halves read src1's low reg)
__device__ __forceinline__ f32x2 pk_fma_blo(f32x2 a, f32x2 b, f32x2 c) {
    f32x2 d;
    asm("v_pk_fma_f32 %0, %1, %2, %3 op_sel:[0,0,0] op_sel_hi:[1,0,1]"
        : "=v"(d) : "v"(a), "v"(b), "v"(c));
    return d;
}
// d = a * broadcast(b.hi) + c
__device__ __forceinline__ f32x2 pk_fma_bhi(f32x2 a, f32x2 b, f32x2 c) {
    f32x2 d;
    asm("v_pk_fma_f32 %0, %1, %2, %3 op_sel:[0,1,0] op_sel_hi:[1,1,1]"
        : "=v"(d) : "v"(a), "v"(b), "v"(c));
    return d;
}
// d = a + broadcast(b.hi)
__device__ __forceinline__ f32x2 pk_add_bhi(f32x2 a, f32x2 b) {
    f32x2 d;
    asm("v_pk_add_f32 %0, %1, %2 op_sel:[0,1] op_sel_hi:[1,1]"
        : "=v"(d) : "v"(a), "v"(b));
    return d;
}

__device__ __forceinline__ float wave_reduce(float v) {
#pragma unroll
    for (int off = 32; off > 0; off >>= 1)
        v += __shfl_down(v, off, 64);
    return v;
}

// Triangle all-pairs sum of 1/r over i<j, coords direct from q/x0
// (free_idx = arange(NFREE): atoms [0,NFREE) from q, rest from x0; slab/tile
// boundaries never straddle NFREE). r2 = si + sj - 2 xi.xj, (-2xi) prescaled.
// Each thread owns 4 CONSECUTIVE atoms: prologue = 3 coalesced float4 loads
// (48B/thread) instead of 12 stride-3 scalar loads.
__global__ __launch_bounds__(TPB) void pair_kernel(const float* __restrict__ q,
                                                   const float* __restrict__ x0,
                                                   float* __restrict__ vpart) {
    __shared__ float4 sj[JT];
    const int bid = blockIdx.x;

    int x = 0;
#pragma unroll
    for (int e = 1; e < GI; ++e) x += (bid >= S_START[e]);
    const int y  = bid - S_START[x] + TPS * x;
    const int i0 = x * TI;
    const int j0 = y * JT;
    const int t  = threadIdx.x;

    // Stage j-tile into LDS as (x, y, z, |x|^2).
    if (t < JT) {
        const int ja = j0 + t;
        const float* p = (ja < NFREE) ? (q + 3 * ja) : (x0 + 3 * ja);
        float xx = p[0], yy = p[1], zz = p[2];
        sj[t] = make_float4(xx, yy, zz, fmaf(xx, xx, fmaf(yy, yy, zz * zz)));
    }

    // i-side: 4 consecutive atoms -> 3 float4 loads (16B-aligned: 12*(i0+4t)%16==0).
    const float* isrc = (i0 < NFREE) ? q : x0;
    const float4* ip = (const float4*)(isrc + 3 * (i0 + 4 * t));
    float4 c0 = ip[0], c1 = ip[1], c2 = ip[2];
    const float xs[IPT] = {c0.x, c0.w, c1.z, c2.y};
    const float ys[IPT] = {c0.y, c1.x, c1.w, c2.z};
    const float zs[IPT] = {c0.z, c1.y, c2.x, c2.w};

    f32x2 ax2[IPT / 2], ay2[IPT / 2], az2[IPT / 2], s2[IPT / 2];
    float acc[IPT];
    int m[IPT];
    const int rel0 = j0 - i0;
#pragma unroll
    for (int k = 0; k < IPT; ++k) {
        ax2[k / 2][k & 1] = -2.f * xs[k];
        ay2[k / 2][k & 1] = -2.f * ys[k];
        az2[k / 2][k & 1] = -2.f * zs[k];
        s2[k / 2][k & 1]  = fmaf(xs[k], xs[k], fmaf(ys[k], ys[k], zs[k] * zs[k]));
        acc[k] = 0.f;
        m[k] = 4 * t + k - rel0;   // keep iff m[k] < j_local (diag band only)
    }
    __syncthreads();

    if (rel0 < TI) {
        // Diagonal-band tile: keep only i<j (select also drops the i==j inf/NaN).
#pragma unroll 8
        for (int j = 0; j < JT; ++j) {
            const float4 pj = sj[j];
            f32x2 pxy; pxy.x = pj.x; pxy.y = pj.y;
            f32x2 pzw; pzw.x = pj.z; pzw.y = pj.w;
#pragma unroll
            for (int g = 0; g < IPT / 2; ++g) {
                f32x2 d = pk_fma_blo(ax2[g], pxy, s2[g]);
                d = pk_fma_bhi(ay2[g], pxy, d);
                d = pk_fma_blo(az2[g], pzw, d);
                d = pk_add_bhi(d, pzw);
                float r0 = __builtin_amdgcn_rsqf(d.x);
                float r1 = __builtin_amdgcn_rsqf(d.y);
                acc[2 * g + 0] += (m[2 * g + 0] < j) ? r0 : 0.f;
                acc[2 * g + 1] += (m[2 * g + 1] < j) ? r1 : 0.f;
            }
        }
    } else {
#pragma unroll 8
        for (int j = 0; j < JT; ++j) {
            const float4 pj = sj[j];
            f32x2 pxy; pxy.x = pj.x; pxy.y = pj.y;
            f32x2 pzw; pzw.x = pj.z; pzw.y = pj.w;
#pragma unroll
            for (int g = 0; g < IPT / 2; ++g) {
                f32x2 d = pk_fma_blo(ax2[g], pxy, s2[g]);
                d = pk_fma_bhi(ay2[g], pxy, d);
                d = pk_fma_blo(az2[g], pzw, d);
                d = pk_add_bhi(d, pzw);
                acc[2 * g + 0] += __builtin_amdgcn_rsqf(d.x);
                acc[2 * g + 1] += __builtin_amdgcn_rsqf(d.y);
            }
        }
    }

    float v = (acc[0] + acc[1]) + (acc[2] + acc[3]);
    v = wave_reduce(v);
    __shared__ float s[TPB / 64];
    int lane = t & 63, wid = t >> 6;
    if (lane == 0) s[wid] = v;
    __syncthreads();
    if (t == 0)
        vpart[bid] = (s[0] + s[1]) + (s[2] + s[3]);
}

// out = 0.5*sum(qd^2) - 2*sum(vpart); single block, deterministic order.
__global__ void finalize(const float* __restrict__ vpart,
                         const float4* __restrict__ qd4,   // qd as 3072 float4
                         float* __restrict__ out) {
    float v = 0.f;
    for (int i = threadIdx.x; i < NVBLK; i += 256) v += vpart[i];
    float tq = 0.f;
    for (int i = threadIdx.x; i < (NFREE * 3) / 4; i += 256) {
        float4 u = qd4[i];
        tq += fmaf(u.x, u.x, fmaf(u.y, u.y, fmaf(u.z, u.z, u.w * u.w)));
    }
    v = wave_reduce(v);
    tq = wave_reduce(tq);
    __shared__ float sv[4], st[4];
    int lane = threadIdx.x & 63, wid = threadIdx.x >> 6;
    if (lane == 0) { sv[wid] = v; st[wid] = tq; }
    __syncthreads();
    if (threadIdx.x == 0) {
        float V = (sv[0] + sv[1]) + (sv[2] + sv[3]);
        float T = (st[0] + st[1]) + (st[2] + st[3]);
        out[0] = 0.5f * T - 2.0f * V;   // V2 = 2 * sum_{i<j} 1/r
    }
}

extern "C" void kernel_launch(void* const* d_in, const int* in_sizes, int n_in,
                              void* d_out, int out_size, void* d_ws, size_t ws_size,
                              hipStream_t stream) {
    const float* q  = (const float*)d_in[0];
    const float* qd = (const float*)d_in[1];
    const float* x0 = (const float*)d_in[2];
    float* out = (float*)d_out;

    float* vpart = (float*)d_ws;

    pair_kernel<<<NVBLK, TPB, 0, stream>>>(q, x0, vpart);
    finalize<<<1, 256, 0, stream>>>(vpart, (const float4*)qd, out);
}